// Round 5
// baseline (902.156 us; speedup 1.0000x reference)
//
#include <hip/hip_runtime.h>
#include <hip/hip_bf16.h>
#include <math.h>

#define N_NODES 100000
#define N_EDGES 3200000
#define IN_F    512
#define HID     16
#define NCLS    40

// ---------------- dtype sniffing for edge_index ------------------------------
// Reference declares int64; harness may hand int32. If int64 little-endian
// (values < 2^31), every odd int32 word is 0. Deterministic data-derived check.
__global__ __launch_bounds__(256) void k_detect(const int* __restrict__ ei,
                                                int* __restrict__ flag) {
    __shared__ int s_nz;
    if (threadIdx.x == 0) s_nz = 0;
    __syncthreads();
    int nz = 0;
    for (int i = threadIdx.x; i < 1024; i += 256)
        if (ei[2 * i + 1] != 0) nz = 1;
    if (nz) atomicOr(&s_nz, 1);
    __syncthreads();
    if (threadIdx.x == 0) flag[0] = s_nz ? 0 : 1;  // 1 => int64 layout
}

__device__ __forceinline__ int load_edge(const void* ei, int is64, int idx) {
    if (is64) return (int)((const long long*)ei)[idx];
    return ((const int*)ei)[idx];
}

// ---------------- CSR build: histogram by dst --------------------------------
__global__ __launch_bounds__(256) void k_zero(int* __restrict__ cnt) {
    int n = blockIdx.x * 256 + threadIdx.x;
    if (n < N_NODES) cnt[n] = 0;
}

__global__ __launch_bounds__(256) void k_hist(const void* __restrict__ ei,
                                              const int* __restrict__ flag,
                                              int* __restrict__ cnt) {
    int e = blockIdx.x * 256 + threadIdx.x;
    if (e >= N_EDGES) return;
    int d = load_edge(ei, flag[0], N_EDGES + e);
    atomicAdd(&cnt[d], 1);
}

// single-block exclusive scan of cnt[N] -> row_start[N+1]
__global__ __launch_bounds__(1024) void k_scan(const int* __restrict__ cnt,
                                               int* __restrict__ row_start) {
    __shared__ int part[1024];
    const int CH = (N_NODES + 1023) / 1024;  // 98
    int t = threadIdx.x;
    int beg = t * CH, end = min(beg + CH, N_NODES);
    int s = 0;
    for (int i = beg; i < end; ++i) s += cnt[i];
    part[t] = s;
    __syncthreads();
    for (int off = 1; off < 1024; off <<= 1) {
        int v = (t >= off) ? part[t - off] : 0;
        __syncthreads();
        part[t] += v;
        __syncthreads();
    }
    int run = (t == 0) ? 0 : part[t - 1];
    for (int i = beg; i < end; ++i) {
        row_start[i] = run;
        run += cnt[i];
    }
    if (t == 0) row_start[N_NODES] = part[1023];
}

// dinv from counts (deg = cnt + 1 self loop)
__global__ __launch_bounds__(256) void k_dinv(const int* __restrict__ cnt,
                                              float* __restrict__ dinv) {
    int n = blockIdx.x * 256 + threadIdx.x;
    if (n < N_NODES) dinv[n] = rsqrtf((float)cnt[n] + 1.0f);
}

// cursor = row_start copy (reuses cnt buffer)
__global__ __launch_bounds__(256) void k_cursor(const int* __restrict__ row_start,
                                                int* __restrict__ cur) {
    int n = blockIdx.x * 256 + threadIdx.x;
    if (n < N_NODES) cur[n] = row_start[n];
}

__global__ __launch_bounds__(256) void k_fill(const void* __restrict__ ei,
                                              const int* __restrict__ flag,
                                              int* __restrict__ cur,
                                              int* __restrict__ csr_src) {
    int e = blockIdx.x * 256 + threadIdx.x;
    if (e >= N_EDGES) return;
    int is64 = flag[0];
    int s = load_edge(ei, is64, e);
    int d = load_edge(ei, is64, N_EDGES + e);
    int pos = atomicAdd(&cur[d], 1);
    csr_src[pos] = s;
}

// ---------------- layer 1 GEMM: h = x @ W1 -----------------------------------
__global__ __launch_bounds__(256) void k_gemm1(const float* __restrict__ x,
                                               const float* __restrict__ W1,
                                               float* __restrict__ h) {
    __shared__ float Ws[IN_F * HID];  // 32 KB
    for (int i = threadIdx.x; i < IN_F * HID; i += 256) Ws[i] = W1[i];
    __syncthreads();
    int n = blockIdx.x * 256 + threadIdx.x;
    if (n >= N_NODES) return;
    float acc[HID];
#pragma unroll
    for (int j = 0; j < HID; ++j) acc[j] = 0.0f;
    const float4* xr = (const float4*)(x + (size_t)n * IN_F);
    for (int k4 = 0; k4 < IN_F / 4; ++k4) {
        float4 xv = xr[k4];
        int kb = k4 * 4;
#pragma unroll
        for (int i = 0; i < 4; ++i) {
            float xs = (&xv.x)[i];
            const float4* wr = (const float4*)(Ws + (kb + i) * HID);
#pragma unroll
            for (int j4 = 0; j4 < 4; ++j4) {
                float4 w = wr[j4];  // same addr across lanes -> LDS broadcast
                acc[j4 * 4 + 0] += xs * w.x;
                acc[j4 * 4 + 1] += xs * w.y;
                acc[j4 * 4 + 2] += xs * w.z;
                acc[j4 * 4 + 3] += xs * w.w;
            }
        }
    }
    float* hn = h + n * HID;
#pragma unroll
    for (int j = 0; j < HID; ++j) hn[j] = acc[j];
}

// ---------------- SpMM gather: out = D^-1/2 (A + I) D^-1/2 feat --------------
// out[n,j] = dinv[n] * ( feat[n,j]*dinv[n] + sum_{s in row n} dinv[s]*feat[s,j] )
__global__ __launch_bounds__(256) void k_spmm(const int* __restrict__ row_start,
                                              const int* __restrict__ csr_src,
                                              const float* __restrict__ dinv,
                                              const float* __restrict__ feat,
                                              float* __restrict__ out) {
    int t = blockIdx.x * 256 + threadIdx.x;
    int n = t >> 4;
    int j = t & 15;
    if (n >= N_NODES) return;
    int beg = row_start[n];
    int end = row_start[n + 1];
    float di = dinv[n];
    float acc = feat[n * HID + j] * di;  // self loop (x di again at the end)
    for (int k = beg; k < end; ++k) {
        int s = csr_src[k];     // uniform across the 16-lane group -> broadcast
        float w = dinv[s];
        acc += feat[s * HID + j] * w;  // 16 lanes = one 64B segment
    }
    out[n * HID + j] = acc * di;
}

// ---------------- relu(agg1+b1) -> h1 ----------------------------------------
__global__ __launch_bounds__(256) void k_relu(const float* __restrict__ agg1,
                                              const float* __restrict__ b1,
                                              float* __restrict__ h1) {
    int t = blockIdx.x * 256 + threadIdx.x;
    if (t >= N_NODES * HID) return;
    int j = t & 15;
    float v = agg1[t] + b1[j];
    h1[t] = fmaxf(v, 0.0f);
}

// ---------------- out = log_softmax(agg2 @ W2 + b2) --------------------------
__global__ __launch_bounds__(256) void k_out(const float* __restrict__ agg2,
                                             const float* __restrict__ W2,
                                             const float* __restrict__ b2,
                                             float* __restrict__ out) {
    __shared__ float Ws[HID * NCLS];  // 2.5 KB
    __shared__ float bs[NCLS];
    for (int i = threadIdx.x; i < HID * NCLS; i += 256) Ws[i] = W2[i];
    for (int i = threadIdx.x; i < NCLS; i += 256) bs[i] = b2[i];
    __syncthreads();
    int n = blockIdx.x * 256 + threadIdx.x;
    if (n >= N_NODES) return;
    float a[HID];
    const float4* ar = (const float4*)(agg2 + n * HID);
#pragma unroll
    for (int q = 0; q < HID / 4; ++q) {
        float4 v = ar[q];
        a[q * 4 + 0] = v.x; a[q * 4 + 1] = v.y;
        a[q * 4 + 2] = v.z; a[q * 4 + 3] = v.w;
    }
    float logits[NCLS];
#pragma unroll
    for (int c = 0; c < NCLS; ++c) logits[c] = bs[c];
#pragma unroll
    for (int k = 0; k < HID; ++k) {
        float av = a[k];
        const float* wr = Ws + k * NCLS;
#pragma unroll
        for (int c = 0; c < NCLS; ++c) logits[c] += av * wr[c];
    }
    float m = logits[0];
#pragma unroll
    for (int c = 1; c < NCLS; ++c) m = fmaxf(m, logits[c]);
    float ssum = 0.0f;
#pragma unroll
    for (int c = 0; c < NCLS; ++c) ssum += expf(logits[c] - m);
    float lse = m + logf(ssum);
    float* on = out + n * NCLS;
#pragma unroll
    for (int c = 0; c < NCLS; ++c) on[c] = logits[c] - lse;
}

// ---------------- launch -----------------------------------------------------
extern "C" void kernel_launch(void* const* d_in, const int* in_sizes, int n_in,
                              void* d_out, int out_size, void* d_ws, size_t ws_size,
                              hipStream_t stream) {
    const float* x  = (const float*)d_in[0];
    const void*  ei = d_in[1];
    const float* W1 = (const float*)d_in[2];
    const float* b1 = (const float*)d_in[3];
    const float* W2 = (const float*)d_in[4];
    const float* b2 = (const float*)d_in[5];
    float* out = (float*)d_out;

    // workspace layout (32-bit words)
    char* wsb = (char*)d_ws;
    int*   cnt  = (int*)wsb;                         // 100000 (reused as cursor)
    int*   row  = (int*)(wsb + 100352 * 4);          // 100001
    float* dinv = (float*)(wsb + 200704 * 4);        // 100000
    float* bufA = (float*)(wsb + 301056 * 4);        // 1.6M  (h, then h1)
    float* bufB = (float*)(wsb + 1901056 * 4);       // 1.6M  (agg1, then agg2)
    int*   csr  = (int*)(wsb + 3501056 * 4);         // 3.2M
    int*   flag = (int*)(wsb + 6701056 * 4);         // 1

    const int B = 256;
    int gN  = (N_NODES + B - 1) / B;                 // 391
    int gE  = (N_EDGES + B - 1) / B;                 // 12500
    int gNH = (N_NODES * HID + B - 1) / B;           // 6250
    int gSP = (N_NODES * HID + B - 1) / B;           // 6250 (16 lanes/node)

    k_detect<<<1, B, 0, stream>>>((const int*)ei, flag);
    k_zero<<<gN, B, 0, stream>>>(cnt);
    k_hist<<<gE, B, 0, stream>>>(ei, flag, cnt);
    k_scan<<<1, 1024, 0, stream>>>(cnt, row);
    k_dinv<<<gN, B, 0, stream>>>(cnt, dinv);
    k_cursor<<<gN, B, 0, stream>>>(row, cnt);        // cnt becomes cursor
    k_fill<<<gE, B, 0, stream>>>(ei, flag, cnt, csr);
    k_gemm1<<<gN, B, 0, stream>>>(x, W1, bufA);                       // h
    k_spmm<<<gSP, B, 0, stream>>>(row, csr, dinv, bufA, bufB);        // agg1
    k_relu<<<gNH, B, 0, stream>>>(bufB, b1, bufA);                    // h1
    k_spmm<<<gSP, B, 0, stream>>>(row, csr, dinv, bufA, bufB);        // agg2
    k_out<<<gN, B, 0, stream>>>(bufB, W2, b2, out);
}

// Round 6
// 730.377 us; speedup vs baseline: 1.2352x; 1.2352x over previous
//
#include <hip/hip_runtime.h>
#include <hip/hip_bf16.h>
#include <math.h>

#define N_NODES 100000
#define N_EDGES 3200000
#define IN_F    512
#define HID     16
#define NCLS    40
#define NB      2048   // node buckets
#define NPB     49     // nodes per bucket (2048*49 = 100352 >= 100000)
#define NBLK    512    // binning blocks
#define EPB     6250   // edges per binning block (512*6250 = 3.2M exactly)

// ---------------- dtype sniffing for edge_index ------------------------------
// Reference declares int64; if int64 little-endian (values < 2^31) every odd
// int32 word is 0. Deterministic data-derived check.
__global__ __launch_bounds__(256) void k_detect(const int* __restrict__ ei,
                                                int* __restrict__ flag) {
    __shared__ int s_nz;
    if (threadIdx.x == 0) s_nz = 0;
    __syncthreads();
    int nz = 0;
    for (int i = threadIdx.x; i < 1024; i += 256)
        if (ei[2 * i + 1] != 0) nz = 1;
    if (nz) atomicOr(&s_nz, 1);
    __syncthreads();
    if (threadIdx.x == 0) flag[0] = s_nz ? 0 : 1;  // 1 => int64 layout
}

__device__ __forceinline__ int load_edge(const void* ei, int is64, int idx) {
    if (is64) return (int)((const long long*)ei)[idx];
    return ((const int*)ei)[idx];
}

// ---------------- zero bucket counters ---------------------------------------
__global__ __launch_bounds__(256) void k_zero(int* __restrict__ g) {
    int i = blockIdx.x * 256 + threadIdx.x;
    if (i < NB) g[i] = 0;
}

// ---------------- bucket histogram (per-block LDS, then global add) ----------
__global__ __launch_bounds__(256) void kH(const void* __restrict__ ei,
                                          const int* __restrict__ flag,
                                          int* __restrict__ gcnt) {
    __shared__ int hist[NB];
    for (int i = threadIdx.x; i < NB; i += 256) hist[i] = 0;
    __syncthreads();
    int is64 = flag[0];
    int off0 = blockIdx.x * EPB;
    for (int i = threadIdx.x; i < EPB; i += 256) {
        int d = load_edge(ei, is64, N_EDGES + off0 + i);
        atomicAdd(&hist[d / NPB], 1);
    }
    __syncthreads();
    for (int i = threadIdx.x; i < NB; i += 256) {
        int c = hist[i];
        if (c) atomicAdd(&gcnt[i], c);
    }
}

// ---------------- scan bucket counts -> bstart[NB+1], cursor -----------------
// NOTE: gcnt and gcur may alias (all reads complete before writes).
__global__ __launch_bounds__(1024) void kS(const int* __restrict__ gcnt,
                                           int* __restrict__ bstart,
                                           int* __restrict__ gcur) {
    __shared__ int part[1024];
    int t = threadIdx.x;
    int a = gcnt[2 * t], b = gcnt[2 * t + 1];
    part[t] = a + b;
    __syncthreads();
    for (int off = 1; off < 1024; off <<= 1) {
        int v = (t >= off) ? part[t - off] : 0;
        __syncthreads();
        part[t] += v;
        __syncthreads();
    }
    int run = (t == 0) ? 0 : part[t - 1];
    bstart[2 * t] = run;     gcur[2 * t] = run;
    bstart[2 * t + 1] = run + a; gcur[2 * t + 1] = run + a;
    if (t == 1023) bstart[NB] = part[1023];
}

// ---------------- bin edges into bucket-contiguous regions -------------------
// packed word = (src << 6) | dst_local   (src < 2^17, dst_local < 49 < 64)
__global__ __launch_bounds__(256) void kB(const void* __restrict__ ei,
                                          const int* __restrict__ flag,
                                          int* __restrict__ gcur,
                                          int* __restrict__ binned) {
    __shared__ int hist[NB];
    __shared__ int base[NB];
    for (int i = threadIdx.x; i < NB; i += 256) hist[i] = 0;
    __syncthreads();
    int is64 = flag[0];
    int off0 = blockIdx.x * EPB;
    for (int i = threadIdx.x; i < EPB; i += 256) {
        int d = load_edge(ei, is64, N_EDGES + off0 + i);
        atomicAdd(&hist[d / NPB], 1);
    }
    __syncthreads();
    for (int i = threadIdx.x; i < NB; i += 256) {
        int c = hist[i];
        base[i] = c ? atomicAdd(&gcur[i], c) : 0;
        hist[i] = 0;  // becomes local cursor
    }
    __syncthreads();
    for (int i = threadIdx.x; i < EPB; i += 256) {
        int s = load_edge(ei, is64, off0 + i);
        int d = load_edge(ei, is64, N_EDGES + off0 + i);
        int b = d / NPB;
        int o = atomicAdd(&hist[b], 1);
        binned[base[b] + o] = (s << 6) | (d - b * NPB);
    }
}

// ---------------- per-bucket degree -> dinv ----------------------------------
__global__ __launch_bounds__(256) void kDeg(const int* __restrict__ bstart,
                                            const int* __restrict__ binned,
                                            float* __restrict__ dinv) {
    __shared__ int ih[NPB];
    int b = blockIdx.x;
    if (threadIdx.x < NPB) ih[threadIdx.x] = 0;
    __syncthreads();
    int beg = bstart[b], end = bstart[b + 1];
    for (int k = beg + threadIdx.x; k < end; k += 256)
        atomicAdd(&ih[binned[k] & 63], 1);
    __syncthreads();
    int i = threadIdx.x;
    if (i < NPB) {
        int n = b * NPB + i;
        if (n < N_NODES) dinv[n] = rsqrtf((float)(ih[i] + 1));  // +1 self loop
    }
}

// ---------------- layer 1 GEMM: hs = (x @ W1) * dinv[n] ----------------------
__global__ __launch_bounds__(256) void k_gemm1(const float* __restrict__ x,
                                               const float* __restrict__ W1,
                                               const float* __restrict__ dinv,
                                               float* __restrict__ hs) {
    __shared__ float Ws[IN_F * HID];  // 32 KB
    for (int i = threadIdx.x; i < IN_F * HID; i += 256) Ws[i] = W1[i];
    __syncthreads();
    int n = blockIdx.x * 256 + threadIdx.x;
    if (n >= N_NODES) return;
    float acc[HID];
#pragma unroll
    for (int j = 0; j < HID; ++j) acc[j] = 0.0f;
    const float4* xr = (const float4*)(x + (size_t)n * IN_F);
    for (int k4 = 0; k4 < IN_F / 4; ++k4) {
        float4 xv = xr[k4];
        int kb = k4 * 4;
#pragma unroll
        for (int i = 0; i < 4; ++i) {
            float xs = (&xv.x)[i];
            const float4* wr = (const float4*)(Ws + (kb + i) * HID);
#pragma unroll
            for (int j4 = 0; j4 < 4; ++j4) {
                float4 w = wr[j4];  // same addr across lanes -> LDS broadcast
                acc[j4 * 4 + 0] += xs * w.x;
                acc[j4 * 4 + 1] += xs * w.y;
                acc[j4 * 4 + 2] += xs * w.z;
                acc[j4 * 4 + 3] += xs * w.w;
            }
        }
    }
    float di = dinv[n];
    float* hn = hs + n * HID;
#pragma unroll
    for (int j = 0; j < HID; ++j) hn[j] = acc[j] * di;
}

// ---------------- bucket aggregation, layer 1 (fused relu+bias+prescale) -----
// h1s[n] = relu( dinv[n]*(sum_s hs[s] + hs[n]) + b1 ) * dinv[n]
__global__ __launch_bounds__(256) void kAgg1(const int* __restrict__ bstart,
                                             const int* __restrict__ binned,
                                             const float* __restrict__ hs,
                                             const float* __restrict__ dinv,
                                             const float* __restrict__ b1,
                                             float* __restrict__ h1s) {
    __shared__ float acc[NPB * 17];  // stride 17 to spread banks
    for (int i = threadIdx.x; i < NPB * 17; i += 256) acc[i] = 0.0f;
    __syncthreads();
    int b = blockIdx.x;
    int beg = bstart[b], end = bstart[b + 1];
    int lane = threadIdx.x & 15;
    for (int k = beg + (threadIdx.x >> 4); k < end; k += 16) {
        int p = binned[k];               // same word for 16 lanes -> broadcast
        int s = p >> 6, dl = p & 63;
        atomicAdd(&acc[dl * 17 + lane], hs[s * 16 + lane]);  // 64B gather
    }
    __syncthreads();
    for (int u = threadIdx.x; u < NPB * 16; u += 256) {
        int i = u >> 4, j = u & 15;
        int n = b * NPB + i;
        if (n < N_NODES) {
            float di = dinv[n];
            float v = di * (acc[i * 17 + j] + hs[n * 16 + j]) + b1[j];
            h1s[n * 16 + j] = fmaxf(v, 0.0f) * di;
        }
    }
}

// ---------------- bucket aggregation, layer 2 --------------------------------
// agg2[n] = dinv[n]*(sum_s h1s[s] + h1s[n])
__global__ __launch_bounds__(256) void kAgg2(const int* __restrict__ bstart,
                                             const int* __restrict__ binned,
                                             const float* __restrict__ h1s,
                                             const float* __restrict__ dinv,
                                             float* __restrict__ agg2) {
    __shared__ float acc[NPB * 17];
    for (int i = threadIdx.x; i < NPB * 17; i += 256) acc[i] = 0.0f;
    __syncthreads();
    int b = blockIdx.x;
    int beg = bstart[b], end = bstart[b + 1];
    int lane = threadIdx.x & 15;
    for (int k = beg + (threadIdx.x >> 4); k < end; k += 16) {
        int p = binned[k];
        int s = p >> 6, dl = p & 63;
        atomicAdd(&acc[dl * 17 + lane], h1s[s * 16 + lane]);
    }
    __syncthreads();
    for (int u = threadIdx.x; u < NPB * 16; u += 256) {
        int i = u >> 4, j = u & 15;
        int n = b * NPB + i;
        if (n < N_NODES) {
            float di = dinv[n];
            agg2[n * 16 + j] = di * (acc[i * 17 + j] + h1s[n * 16 + j]);
        }
    }
}

// ---------------- out = log_softmax(agg2 @ W2 + b2) --------------------------
__global__ __launch_bounds__(256) void k_out(const float* __restrict__ agg2,
                                             const float* __restrict__ W2,
                                             const float* __restrict__ b2,
                                             float* __restrict__ out) {
    __shared__ float Ws[HID * NCLS];
    __shared__ float bs[NCLS];
    for (int i = threadIdx.x; i < HID * NCLS; i += 256) Ws[i] = W2[i];
    for (int i = threadIdx.x; i < NCLS; i += 256) bs[i] = b2[i];
    __syncthreads();
    int n = blockIdx.x * 256 + threadIdx.x;
    if (n >= N_NODES) return;
    float a[HID];
    const float4* ar = (const float4*)(agg2 + n * HID);
#pragma unroll
    for (int q = 0; q < HID / 4; ++q) {
        float4 v = ar[q];
        a[q * 4 + 0] = v.x; a[q * 4 + 1] = v.y;
        a[q * 4 + 2] = v.z; a[q * 4 + 3] = v.w;
    }
    float logits[NCLS];
#pragma unroll
    for (int c = 0; c < NCLS; ++c) logits[c] = bs[c];
#pragma unroll
    for (int k = 0; k < HID; ++k) {
        float av = a[k];
        const float* wr = Ws + k * NCLS;
#pragma unroll
        for (int c = 0; c < NCLS; ++c) logits[c] += av * wr[c];
    }
    float m = logits[0];
#pragma unroll
    for (int c = 1; c < NCLS; ++c) m = fmaxf(m, logits[c]);
    float ssum = 0.0f;
#pragma unroll
    for (int c = 0; c < NCLS; ++c) ssum += expf(logits[c] - m);
    float lse = m + logf(ssum);
    float* on = out + n * NCLS;
#pragma unroll
    for (int c = 0; c < NCLS; ++c) on[c] = logits[c] - lse;
}

// ---------------- launch -----------------------------------------------------
extern "C" void kernel_launch(void* const* d_in, const int* in_sizes, int n_in,
                              void* d_out, int out_size, void* d_ws, size_t ws_size,
                              hipStream_t stream) {
    const float* x  = (const float*)d_in[0];
    const void*  ei = d_in[1];
    const float* W1 = (const float*)d_in[2];
    const float* b1 = (const float*)d_in[3];
    const float* W2 = (const float*)d_in[4];
    const float* b2 = (const float*)d_in[5];
    float* out = (float*)d_out;

    // workspace layout (32-bit words); total 6,513,664 words = 26.05 MB
    int*   iws    = (int*)d_ws;
    float* fws    = (float*)d_ws;
    int*   gcur   = iws;                 // [2048] counts, then cursor
    int*   bstart = iws + 2048;          // [2049]
    int*   flag   = iws + 4104;          // [1]
    float* dinv   = fws + 8192;          // [100000]
    float* hs     = fws + 110592;        // [1.6M]  (hs, later aliased as agg2)
    float* h1s    = fws + 1712128;       // [1.6M]
    int*   binned = iws + 3313664;       // [3.2M]
    float* agg2   = hs;                  // alias: hs dead after kAgg1

    const int B = 256;
    int gN = (N_NODES + B - 1) / B;      // 391

    k_detect<<<1, B, 0, stream>>>((const int*)ei, flag);
    k_zero<<<(NB + B - 1) / B, B, 0, stream>>>(gcur);
    kH<<<NBLK, B, 0, stream>>>(ei, flag, gcur);
    kS<<<1, 1024, 0, stream>>>(gcur, bstart, gcur);
    kB<<<NBLK, B, 0, stream>>>(ei, flag, gcur, binned);
    kDeg<<<NB, B, 0, stream>>>(bstart, binned, dinv);
    k_gemm1<<<gN, B, 0, stream>>>(x, W1, dinv, hs);
    kAgg1<<<NB, B, 0, stream>>>(bstart, binned, hs, dinv, b1, h1s);
    kAgg2<<<NB, B, 0, stream>>>(bstart, binned, h1s, dinv, agg2);
    k_out<<<gN, B, 0, stream>>>(agg2, W2, b2, out);
}